// Round 15
// baseline (689.247 us; speedup 1.0000x reference)
//
#include <hip/hip_runtime.h>
#include <hip/hip_bf16.h>
#include <stdint.h>

#define S_LEN 2048
#define D_HEAD 64
#define NBH 64            // B*H = 4*16
#define QBLK 64
#define KBLK 64
#define NITER (S_LEN / KBLK)   // 32

// Q pre-scale: 1/sqrt(64) * log2(e), so scores feed exp2f directly
#define QSCALE 0.1803368801111244f

typedef __attribute__((ext_vector_type(8))) short short8;  // 8 x bf16
typedef __attribute__((ext_vector_type(4))) float f32x4;

// ---------------- fast-path LDS (50 KB -> 3 blocks/CU, 24 waves) ----------------
#define KB_OFF   0        // 3 x 8KB K triple buffer
#define VT_OFF   24576    // 2 x 8KB Vt double buffer
#define PRED_OFF 40960    // 2KB pred ring: [iter&3][row 64][8B]
#define P_OFF    43008    // 8KB P tile (Q staging in prologue; LP overlay)
#define LP_OFF   43008    // 512B row-sum partials (transient, inside P region)
#define SMEM_BYTES 51200

// ---------------- fallback LDS layout ----------------
#define FK_OFF  0
#define FVT_OFF 16384
#define FP_OFF  24576
#define FMB_OFF 28672
#define FLP_OFF 36864
#define FSMEM_BYTES 37120

__device__ __forceinline__ int swz1(int row, int b) {
  return row * 128 + (b ^ ((row & 7) << 4));
}
__device__ __forceinline__ int swz2(int row, int b) {
  return row * 128 + (b ^ (((row >> 1) & 7) << 4));
}

__device__ __forceinline__ short f2b(float x) {  // fp32 -> bf16 RNE
  unsigned u = __float_as_uint(x);
  unsigned r = 0x7FFFu + ((u >> 16) & 1u);
  return (short)((u + r) >> 16);
}
__device__ __forceinline__ float b2f(short s) {
  return __uint_as_float(((unsigned)(unsigned short)s) << 16);
}

__device__ __forceinline__ void gload_lds16(const void* g, void* l) {
  __builtin_amdgcn_global_load_lds(
      (const __attribute__((address_space(1))) unsigned int*)g,
      (__attribute__((address_space(3))) unsigned int*)l, 16, 0, 0);
}

// counted-vmcnt barrier (T3/T4): loads/stores stay in flight across the barrier
#define WAITBAR(N) do { \
  asm volatile("s_waitcnt vmcnt(" #N ") lgkmcnt(0)" ::: "memory"); \
  __builtin_amdgcn_s_barrier(); } while (0)
#define LGKMBAR() do { \
  asm volatile("s_waitcnt lgkmcnt(0)" ::: "memory"); \
  __builtin_amdgcn_s_barrier(); } while (0)

// Detect mask element width (int32 words are in {0,1,0x3F800000}).
__global__ void detect_mask_kernel(const unsigned* m, int* flag) {
  unsigned v = m[blockIdx.x * 256 + threadIdx.x];
  if (v != 0u && v != 1u && v != 0x3F800000u) atomicOr(flag, 1);
}

// fp32 -> bf16, linear (for K)
__global__ void __launch_bounds__(256) convK_kernel(
    const float* __restrict__ in, short* __restrict__ out) {
  size_t i = ((size_t)blockIdx.x * 256 + threadIdx.x) * 8;
  float4 a = ((const float4*)(in + i))[0];
  float4 b = ((const float4*)(in + i))[1];
  short8 v;
  v[0] = f2b(a.x); v[1] = f2b(a.y); v[2] = f2b(a.z); v[3] = f2b(a.w);
  v[4] = f2b(b.x); v[5] = f2b(b.y); v[6] = f2b(b.z); v[7] = f2b(b.w);
  *(short8*)(out + i) = v;
}

// fp32 V[bh][s][d] -> bf16 Vt[bh][d][s]
__global__ void __launch_bounds__(256) convVT_kernel(
    const float* __restrict__ V, short* __restrict__ out) {
  __shared__ __align__(16) short t[64 * 72];
  int tid = threadIdx.x;
  int kb = blockIdx.x * 64, bh = blockIdx.y;
  const float* src = V + ((size_t)bh * S_LEN + kb) * D_HEAD;
#pragma unroll
  for (int j = 0; j < 4; ++j) {
    int key = j * 16 + (tid >> 4), d0 = (tid & 15) * 4;
    float4 f = *(const float4*)(src + (size_t)key * D_HEAD + d0);
    t[(d0 + 0) * 72 + key] = f2b(f.x);
    t[(d0 + 1) * 72 + key] = f2b(f.y);
    t[(d0 + 2) * 72 + key] = f2b(f.z);
    t[(d0 + 3) * 72 + key] = f2b(f.w);
  }
  __syncthreads();
  int row = tid >> 2, seg = tid & 3;
  short8 v0 = *(const short8*)(t + row * 72 + seg * 16);
  short8 v1 = *(const short8*)(t + row * 72 + seg * 16 + 8);
  short* dst = out + (size_t)bh * D_HEAD * S_LEN + (size_t)row * S_LEN + kb + seg * 16;
  *(short8*)dst = v0;
  *(short8*)(dst + 8) = v1;
}

// ======================= FAST PATH (QBLK=64, 8 waves, pred ring, 3 blk/CU) =======================
template <bool BYTEMASK>
__device__ __forceinline__ void attn_fast(
    char* smem, const float* __restrict__ Qg, const void* __restrict__ maskg,
    const short* __restrict__ Kbf, const short* __restrict__ Vtb,
    float* __restrict__ ctxg, float* __restrict__ attng,
    int qb, int bh) {

  const int tid = threadIdx.x;
  const int w = tid >> 6, l = tid & 63;
  const int lg = l >> 4, li = l & 15;
  const int rh = w >> 1, ch = w & 1;          // wave -> (row-quarter, col-half)
  const int qbase = qb * QBLK;
  const int row = tid >> 3, seg = tid & 7;    // staging layout: 8 threads/row, 64 rows

  const float* Qp = Qg + ((size_t)bh * S_LEN + qbase) * D_HEAD;
  const short* Kbp = Kbf + (size_t)bh * S_LEN * D_HEAD;
  const short* Vtp = Vtb + (size_t)bh * D_HEAD * S_LEN;
  float* attnp = attng + ((size_t)bh * S_LEN + qbase) * S_LEN;
  float* ctxp  = ctxg  + ((size_t)bh * S_LEN + qbase) * D_HEAD;
  const size_t mbase = ((size_t)bh * S_LEN + qbase + row) * S_LEN + seg * 8;

  auto stageK = [&](int it) {               // -> kb[it % 3]; 1 instr/thread
    const int buf = it % 3;
    const short* src = Kbp + ((size_t)(it * KBLK + row)) * D_HEAD + ((seg ^ (row & 7)) * 8);
    int off = __builtin_amdgcn_readfirstlane(buf * 8192 + w * 1024);
    gload_lds16(src, smem + KB_OFF + off);
  };
  auto stageVt = [&](int it) {              // -> vt[it & 1]; 1 instr/thread
    const int buf = it & 1;
    const short* src = Vtp + (size_t)row * S_LEN + it * KBLK + ((seg ^ (row & 7)) * 8);
    int off = __builtin_amdgcn_readfirstlane(buf * 8192 + w * 1024);
    gload_lds16(src, smem + VT_OFF + off);
  };

  auto qkt = [&](f32x4* accs, const short8* qf, int it) {
    char* kb = smem + KB_OFF + (it % 3) * 8192;
#pragma unroll
    for (int ct = 0; ct < 2; ++ct) {
      int key = ch * 32 + ct * 16 + li;
      short8 b0 = *(const short8*)(kb + swz1(key, lg * 16));
      short8 b1 = *(const short8*)(kb + swz1(key, 64 + lg * 16));
      accs[ct] = __builtin_amdgcn_mfma_f32_16x16x32_bf16(qf[0], b0, accs[ct], 0, 0, 0);
      accs[ct] = __builtin_amdgcn_mfma_f32_16x16x32_bf16(qf[1], b1, accs[ct], 0, 0, 0);
    }
  };

  struct MaskRegs { int4 a, b; uint2 c; };
  auto loadMask = [&](int it, MaskRegs& m) {
    if constexpr (BYTEMASK) {
      m.c = *(const uint2*)((const unsigned char*)maskg + mbase + it * KBLK);
    } else {
      const int* p = (const int*)maskg + mbase + it * KBLK;
      m.a = *(const int4*)p;
      m.b = *(const int4*)(p + 4);
    }
  };
  auto predWrite = [&](int it, const MaskRegs& m) {   // -> ring slot it&3
    unsigned pb = 0;
    if constexpr (BYTEMASK) {
      unsigned lo = m.c.x, hi = m.c.y;
#pragma unroll
      for (int j = 0; j < 4; ++j) {
        pb |= (((lo >> (8 * j)) & 255u) != 0u ? 1u : 0u) << j;
        pb |= (((hi >> (8 * j)) & 255u) != 0u ? 1u : 0u) << (j + 4);
      }
    } else {
      pb |= (m.a.x != 0) ? 1u : 0u;
      pb |= (m.a.y != 0) ? 2u : 0u;
      pb |= (m.a.z != 0) ? 4u : 0u;
      pb |= (m.a.w != 0) ? 8u : 0u;
      pb |= (m.b.x != 0) ? 16u : 0u;
      pb |= (m.b.y != 0) ? 32u : 0u;
      pb |= (m.b.z != 0) ? 64u : 0u;
      pb |= (m.b.w != 0) ? 128u : 0u;
    }
    *(unsigned char*)(smem + PRED_OFF + (it & 3) * 512 + row * 8 + seg) = (unsigned char)pb;
  };

  // ---- prologue: issue mask + K loads early, stage Q (pre-scaled) ----
  MaskRegs t0, t1, mA, mB;
  loadMask(0, t0); loadMask(1, t1); loadMask(2, mA); loadMask(3, mB);
  stageK(0); stageK(1);
  {
    const float* src = Qp + row * D_HEAD + seg * 8;
    float4 a = ((const float4*)src)[0];
    float4 b = ((const float4*)src)[1];
    short8 v;
    v[0] = f2b(a.x * QSCALE); v[1] = f2b(a.y * QSCALE);
    v[2] = f2b(a.z * QSCALE); v[3] = f2b(a.w * QSCALE);
    v[4] = f2b(b.x * QSCALE); v[5] = f2b(b.y * QSCALE);
    v[6] = f2b(b.z * QSCALE); v[7] = f2b(b.w * QSCALE);
    *(short8*)(smem + P_OFF + swz1(row, seg * 16)) = v;
  }
  __syncthreads();   // Q visible; drains vmcnt(0) -> sK(0), sK(1) complete
  short8 qfrag[2];
  {
    int qr = rh * 16 + li;            // 0..63
    qfrag[0] = *(const short8*)(smem + P_OFF + swz1(qr, lg * 16));
    qfrag[1] = *(const short8*)(smem + P_OFF + swz1(qr, 64 + lg * 16));
  }
  predWrite(0, t0);
  predWrite(1, t1);

  // ===== pass 1: row sums of exp2(s); per-thread partials (reduce hoisted) =====
  float l_acc[4] = {0.f, 0.f, 0.f, 0.f};
  auto p1iter = [&](int i, MaskRegs& m) {
    f32x4 accs[2] = {{0.f,0.f,0.f,0.f},{0.f,0.f,0.f,0.f}};
    qkt(accs, qfrag, i);
    if (i <= 27) {
      if constexpr (BYTEMASK) WAITBAR(1); else WAITBAR(2);
    } else {
      WAITBAR(0);
    }
    if (i + 2 < NITER) stageK(i + 2);
    if (i + 2 < NITER) predWrite(i + 2, m);
    if (i + 4 < NITER) loadMask(i + 4, m);
#pragma unroll
    for (int reg = 0; reg < 4; ++reg) {
      int rw = rh * 16 + lg * 4 + reg;
      unsigned long long p64 =
          *(const unsigned long long*)(smem + PRED_OFF + (i & 3) * 512 + rw * 8);
      unsigned pw = (unsigned)(p64 >> (ch << 5));
      float e0 = ((pw >> li) & 1u)        ? 0.f : exp2f(accs[0][reg]);
      float e1 = ((pw >> (16 + li)) & 1u) ? 0.f : exp2f(accs[1][reg]);
      l_acc[reg] += e0 + e1;              // reduce once after the loop
    }
  };
  for (int i = 0; i < NITER; i += 2) {
    p1iter(i, mA);        // static call sites only
    p1iter(i + 1, mB);
  }

  // ---- transition: one-shot reduce, LP, prefetch pass-2 tiles + masks ----
#pragma unroll
  for (int reg = 0; reg < 4; ++reg) {
    float s = l_acc[reg];
    s += __shfl_xor(s, 1);
    s += __shfl_xor(s, 2);
    s += __shfl_xor(s, 4);
    s += __shfl_xor(s, 8);
    l_acc[reg] = s;
  }
  if (li == 0) {
#pragma unroll
    for (int reg = 0; reg < 4; ++reg)
      *(float*)(smem + LP_OFF + ch * 256 + (rh * 16 + lg * 4 + reg) * 4) = l_acc[reg];
  }
  stageK(0); stageK(1); stageVt(0);
  loadMask(0, t0); loadMask(1, t1); loadMask(2, mA); loadMask(3, mB);
  WAITBAR(0);   // drain everything once; LP visible
  predWrite(0, t0);
  predWrite(1, t1);
  float linv[4];
#pragma unroll
  for (int reg = 0; reg < 4; ++reg) {
    int rw = rh * 16 + lg * 4 + reg;
    linv[reg] = 1.0f / (*(const float*)(smem + LP_OFF + rw * 4) +
                        *(const float*)(smem + LP_OFF + 256 + rw * 4));
  }
  float* arow = attnp + (size_t)row * S_LEN + seg * 8;

  // ===== pass 2: recompute S, P->LDS, contiguous attn store-back, PV =====
  f32x4 acco[2] = {{0.f,0.f,0.f,0.f},{0.f,0.f,0.f,0.f}};
  auto p2iter = [&](int i, MaskRegs& m) {
    f32x4 accs[2] = {{0.f,0.f,0.f,0.f},{0.f,0.f,0.f,0.f}};
    qkt(accs, qfrag, i);
    // BARRIER_A (lgkm only): all waves past qkt(i)/PV(i-1)/store-back reads -> WAR safe
    LGKMBAR();
    if (i + 2 < NITER) stageK(i + 2);
    if (i + 1 < NITER) stageVt(i + 1);
    if (i + 2 < NITER) predWrite(i + 2, m);
    if (i + 4 < NITER) loadMask(i + 4, m);
#pragma unroll
    for (int reg = 0; reg < 4; ++reg) {
      int rw = rh * 16 + lg * 4 + reg;
      unsigned long long p64 =
          *(const unsigned long long*)(smem + PRED_OFF + (i & 3) * 512 + rw * 8);
      unsigned pw = (unsigned)(p64 >> (ch << 5));
      float e0 = ((pw >> li) & 1u)        ? 0.f : exp2f(accs[0][reg]) * linv[reg];
      float e1 = ((pw >> (16 + li)) & 1u) ? 0.f : exp2f(accs[1][reg]) * linv[reg];
      *(short*)(smem + P_OFF + swz2(rw, (ch * 32 + li) * 2)) = f2b(e0);
      *(short*)(smem + P_OFF + swz2(rw, (ch * 32 + 16 + li) * 2)) = f2b(e1);
    }
    // BARRIER_B: P visible; drain through sVt(i); keep stores + newer stages in flight
    if (i == 0) {
      if constexpr (BYTEMASK) WAITBAR(3); else WAITBAR(4);
    } else if (i <= 27) {
      if constexpr (BYTEMASK) WAITBAR(5); else WAITBAR(6);
    } else {
      WAITBAR(2);
    }
    // attn store-back from LDS: 256B contiguous per 8-lane row group
    {
      short8 pv = *(const short8*)(smem + P_OFF + swz2(row, seg * 16));
      float4 f0, f1;
      f0.x = b2f(pv[0]); f0.y = b2f(pv[1]); f0.z = b2f(pv[2]); f0.w = b2f(pv[3]);
      f1.x = b2f(pv[4]); f1.y = b2f(pv[5]); f1.z = b2f(pv[6]); f1.w = b2f(pv[7]);
      ((float4*)(arow + i * KBLK))[0] = f0;
      *(float4*)(arow + i * KBLK + 4) = f1;
    }
    // PV: O(16x32 per wave) += P(16x64) * V(64xD tile)
    {
      char* vb = smem + VT_OFF + (i & 1) * 8192;
#pragma unroll
      for (int ks = 0; ks < 2; ++ks) {
        int prow = rh * 16 + li;
        short8 af = *(const short8*)(smem + P_OFF + swz2(prow, ks * 64 + lg * 16));
#pragma unroll
        for (int ct2 = 0; ct2 < 2; ++ct2) {
          int d = ch * 32 + ct2 * 16 + li;
          short8 bf = *(const short8*)(vb + swz1(d, ks * 64 + lg * 16));
          acco[ct2] = __builtin_amdgcn_mfma_f32_16x16x32_bf16(af, bf, acco[ct2], 0, 0, 0);
        }
      }
    }
  };
  for (int i = 0; i < NITER; i += 2) {
    p2iter(i, mA);        // static call sites only (no runtime-selected reference)
    p2iter(i + 1, mB);
  }

  // epilogue: P was normalized -> ctx = acco
#pragma unroll
  for (int ct2 = 0; ct2 < 2; ++ct2)
#pragma unroll
    for (int reg = 0; reg < 4; ++reg) {
      int rw = rh * 16 + lg * 4 + reg;
      int d = ch * 32 + ct2 * 16 + li;
      ctxp[(size_t)rw * D_HEAD + d] = acco[ct2][reg];
    }
}

__global__ void __launch_bounds__(512, 4)
attn_fast_kernel(const float* Q, const void* M, const short* Kbf, const short* Vtb,
                 float* ctx, float* attn, const int* flag) {
  __shared__ __align__(16) char smem[SMEM_BYTES];
  int bid = blockIdx.x;
  int s = ((bid & 7) << 8) | (bid >> 3);   // XCD-bijective swizzle (2048 = 8*256)
  int bh = s >> 5, qb = s & 31;            // 32 q-blocks of 64 rows per head
  if (*flag)
    attn_fast<true>(smem, Q, M, Kbf, Vtb, ctx, attn, qb, bh);
  else
    attn_fast<false>(smem, Q, M, Kbf, Vtb, ctx, attn, qb, bh);
}

// ======================= FALLBACK (round-2 body; no workspace needed) =======================
template <bool BYTEMASK>
__device__ __forceinline__ void attn_body(
    char* smem, const float* Qg, const float* Kg, const float* Vg,
    const void* maskg, float* ctxg, float* attng) {

  const int tid = threadIdx.x;
  const int w = tid >> 6, l = tid & 63;
  const int lg = l >> 4, li = l & 15;
  const int rh = w >> 1, ch = w & 1;
  const int qb = blockIdx.x, bh = blockIdx.y;
  const int qbase = qb * 32;

  const float* Qp = Qg + ((size_t)bh * S_LEN + qbase) * D_HEAD;
  const float* Kp = Kg + (size_t)bh * S_LEN * D_HEAD;
  const float* Vp = Vg + (size_t)bh * S_LEN * D_HEAD;
  float* attnp = attng + ((size_t)bh * S_LEN + qbase) * S_LEN;
  float* ctxp  = ctxg  + ((size_t)bh * S_LEN + qbase) * D_HEAD;
  const size_t mrow0 = ((size_t)bh * S_LEN + qbase) * S_LEN;

  auto stageK = [&](int it, int buf) {
    char* kb = smem + FK_OFF + buf * 8192;
    int key = tid >> 2, seg = tid & 3;
    const float* src = Kp + ((size_t)(it * KBLK + key)) * D_HEAD + seg * 16;
    float4 f0 = ((const float4*)src)[0];
    float4 f1 = ((const float4*)src)[1];
    float4 f2 = ((const float4*)src)[2];
    float4 f3 = ((const float4*)src)[3];
    short8 v0, v1;
    v0[0] = f2b(f0.x); v0[1] = f2b(f0.y); v0[2] = f2b(f0.z); v0[3] = f2b(f0.w);
    v0[4] = f2b(f1.x); v0[5] = f2b(f1.y); v0[6] = f2b(f1.z); v0[7] = f2b(f1.w);
    v1[0] = f2b(f2.x); v1[1] = f2b(f2.y); v1[2] = f2b(f2.z); v1[3] = f2b(f2.w);
    v1[4] = f2b(f3.x); v1[5] = f2b(f3.y); v1[6] = f2b(f3.z); v1[7] = f2b(f3.w);
    *(short8*)(kb + swz1(key, seg * 32)) = v0;
    *(short8*)(kb + swz1(key, seg * 32 + 16)) = v1;
  };

  auto stageVt = [&](int it) {
    char* vb = smem + FVT_OFF;
    int key = l, db = w;
    const float* src = Vp + ((size_t)(it * KBLK + key)) * D_HEAD + db * 16;
#pragma unroll
    for (int j = 0; j < 4; ++j) {
      float4 f = ((const float4*)src)[j];
      int dd = db * 16 + j * 4;
      *(short*)(vb + swz1(dd + 0, key * 2)) = f2b(f.x);
      *(short*)(vb + swz1(dd + 1, key * 2)) = f2b(f.y);
      *(short*)(vb + swz1(dd + 2, key * 2)) = f2b(f.z);
      *(short*)(vb + swz1(dd + 3, key * 2)) = f2b(f.w);
    }
  };

  auto loadMask = [&](int it, unsigned* m) {
#pragma unroll
    for (int reg = 0; reg < 4; ++reg) {
      int rw = rh * 16 + lg * 4 + reg;
#pragma unroll
      for (int ct = 0; ct < 2; ++ct) {
        size_t idx = mrow0 + (size_t)rw * S_LEN + it * KBLK + ch * 32 + ct * 16 + li;
        if constexpr (BYTEMASK)
          m[ct * 4 + reg] = (unsigned)((const unsigned char*)maskg)[idx];
        else
          m[ct * 4 + reg] = ((const unsigned*)maskg)[idx];
      }
    }
  };

  auto qkt = [&](f32x4* accs, const short8* qf, int buf) {
    char* kb = smem + FK_OFF + buf * 8192;
#pragma unroll
    for (int ct = 0; ct < 2; ++ct) {
      int key = ch * 32 + ct * 16 + li;
      short8 b0 = *(const short8*)(kb + swz1(key, lg * 16));
      short8 b1 = *(const short8*)(kb + swz1(key, 64 + lg * 16));
      accs[ct] = __builtin_amdgcn_mfma_f32_16x16x32_bf16(qf[0], b0, accs[ct], 0, 0, 0);
      accs[ct] = __builtin_amdgcn_mfma_f32_16x16x32_bf16(qf[1], b1, accs[ct], 0, 0, 0);
    }
  };

  stageK(0, 0);
  unsigned mc[8];
  loadMask(0, mc);
  {
    int rw = tid >> 3, seg = tid & 7;
    const float* src = Qp + rw * D_HEAD + seg * 8;
    float4 a = ((const float4*)src)[0];
    float4 b = ((const float4*)src)[1];
    short8 v;
    v[0] = f2b(a.x); v[1] = f2b(a.y); v[2] = f2b(a.z); v[3] = f2b(a.w);
    v[4] = f2b(b.x); v[5] = f2b(b.y); v[6] = f2b(b.z); v[7] = f2b(b.w);
    *(short8*)(smem + FP_OFF + swz1(rw, seg * 16)) = v;
  }
  __syncthreads();
  short8 qfrag[2];
  {
    int rw = rh * 16 + li;
    qfrag[0] = *(const short8*)(smem + FP_OFF + swz1(rw, lg * 16));
    qfrag[1] = *(const short8*)(smem + FP_OFF + swz1(rw, 64 + lg * 16));
  }
  __syncthreads();

  float l_acc[4] = {0.f, 0.f, 0.f, 0.f};
  for (int it = 0; it < NITER; ++it) {
    const int cb = it & 1, nb = cb ^ 1;
    if (it + 1 < NITER) stageK(it + 1, nb);
    unsigned mn[8];
    if (it + 1 < NITER) loadMask(it + 1, mn);
    f32x4 accs[2] = {{0.f,0.f,0.f,0.f},{0.f,0.f,0.f,0.f}};
    qkt(accs, qfrag, cb);
    unsigned mbyte = 0;
#pragma unroll
    for (int reg = 0; reg < 4; ++reg) {
      float contrib = 0.f;
#pragma unroll
      for (int ct = 0; ct < 2; ++ct) {
        bool pred = mc[ct * 4 + reg] != 0u;
        mbyte |= (unsigned)pred << (ct * 4 + reg);
        float pp = pred ? 0.f : __expf(accs[ct][reg] * 0.125f);
        contrib += pp;
      }
      contrib += __shfl_xor(contrib, 1);
      contrib += __shfl_xor(contrib, 2);
      contrib += __shfl_xor(contrib, 4);
      contrib += __shfl_xor(contrib, 8);
      l_acc[reg] += contrib;
    }
    *(unsigned char*)(smem + FMB_OFF + it * 256 + tid) = (unsigned char)mbyte;
    __syncthreads();
    if (it + 1 < NITER) {
#pragma unroll
      for (int i = 0; i < 8; ++i) mc[i] = mn[i];
    }
  }

  if (li == 0) {
#pragma unroll
    for (int reg = 0; reg < 4; ++reg)
      *(float*)(smem + FLP_OFF + ch * 128 + (rh * 16 + lg * 4 + reg) * 4) = l_acc[reg];
  }
  stageK(0, 0);
  stageVt(0);
  __syncthreads();
  float linv[4];
#pragma unroll
  for (int reg = 0; reg < 4; ++reg) {
    int rw = rh * 16 + lg * 4 + reg;
    linv[reg] = 1.0f / (*(const float*)(smem + FLP_OFF + rw * 4) +
                        *(const float*)(smem + FLP_OFF + 128 + rw * 4));
  }

  f32x4 acco[2] = {{0.f,0.f,0.f,0.f},{0.f,0.f,0.f,0.f}};
  for (int it = 0; it < NITER; ++it) {
    const int cb = it & 1, nb = cb ^ 1;
    if (it > 0) stageVt(it);
    if (it + 1 < NITER) stageK(it + 1, nb);
    f32x4 accs[2] = {{0.f,0.f,0.f,0.f},{0.f,0.f,0.f,0.f}};
    qkt(accs, qfrag, cb);
    unsigned mbyte = *(const unsigned char*)(smem + FMB_OFF + it * 256 + tid);
#pragma unroll
    for (int reg = 0; reg < 4; ++reg) {
      int rw = rh * 16 + lg * 4 + reg;
#pragma unroll
      for (int ct = 0; ct < 2; ++ct) {
        int col = ch * 32 + ct * 16 + li;
        bool pred = (mbyte >> (ct * 4 + reg)) & 1u;
        float pp = pred ? 0.f : __expf(accs[ct][reg] * 0.125f) * linv[reg];
        attnp[(size_t)rw * S_LEN + it * KBLK + col] = pp;
        *(short*)(smem + FP_OFF + swz2(rw, col * 2)) = f2b(pp);
      }
    }
    __syncthreads();
#pragma unroll
    for (int ks = 0; ks < 2; ++ks) {
      int prow = rh * 16 + li;
      short8 af = *(const short8*)(smem + FP_OFF + swz2(prow, ks * 64 + lg * 16));
#pragma unroll
      for (int ct2 = 0; ct2 < 2; ++ct2) {
        int d = ch * 32 + ct2 * 16 + li;
        short8 bf = *(const short8*)(smem + FVT_OFF + swz1(d, ks * 64 + lg * 16));
        acco[ct2] = __builtin_amdgcn_mfma_f32_16x16x32_bf16(af, bf, acco[ct2], 0, 0, 0);
      }
    }
    __syncthreads();
  }

#pragma unroll
  for (int ct2 = 0; ct2 < 2; ++ct2) {
#pragma unroll
    for (int reg = 0; reg < 4; ++reg) {
      int rw = rh * 16 + lg * 4 + reg;
      int d = ch * 32 + ct2 * 16 + li;
      ctxp[(size_t)rw * D_HEAD + d] = acco[ct2][reg];
    }
  }
}

__global__ void __launch_bounds__(256, 4)
attn_kernel(const float* Q, const float* K, const float* V, const void* M,
            float* ctx, float* attn, const int* flag) {
  extern __shared__ char smem[];
  if (*flag)
    attn_body<true>(smem, Q, K, V, M, ctx, attn);
  else
    attn_body<false>(smem, Q, K, V, M, ctx, attn);
}

extern "C" void kernel_launch(void* const* d_in, const int* in_sizes, int n_in,
                              void* d_out, int out_size, void* d_ws, size_t ws_size,
                              hipStream_t stream) {
  const float* Q = (const float*)d_in[0];
  const float* K = (const float*)d_in[1];
  const float* V = (const float*)d_in[2];
  const void*  M = d_in[3];
  float* ctx  = (float*)d_out;
  float* attn = ctx + (size_t)NBH * S_LEN * D_HEAD;
  int* flag = (int*)d_ws;
  short* Kbf = (short*)((char*)d_ws + 256);
  short* Vtb = Kbf + (size_t)NBH * S_LEN * D_HEAD;
  const size_t PRE_BYTES = 256 + (size_t)2 * NBH * S_LEN * D_HEAD * sizeof(short);

  hipMemsetAsync(flag, 0, sizeof(int), stream);
  detect_mask_kernel<<<dim3(16), dim3(256), 0, stream>>>((const unsigned*)M, flag);

  if (ws_size >= PRE_BYTES) {
    convK_kernel<<<dim3(4096), dim3(256), 0, stream>>>(K, Kbf);
    convVT_kernel<<<dim3(32, 64), dim3(256), 0, stream>>>(V, Vtb);
    attn_fast_kernel<<<dim3(2048), dim3(512), 0, stream>>>(
        Q, M, Kbf, Vtb, ctx, attn, flag);
  } else {
    dim3 grid(S_LEN / 32, NBH);
    attn_kernel<<<grid, dim3(256), FSMEM_BYTES, stream>>>(
        Q, K, V, M, ctx, attn, flag);
  }
}

// Round 16
// 565.289 us; speedup vs baseline: 1.2193x; 1.2193x over previous
//
#include <hip/hip_runtime.h>
#include <hip/hip_bf16.h>
#include <stdint.h>

#define S_LEN 2048
#define D_HEAD 64
#define NBH 64            // B*H = 4*16
#define QBLK 64
#define KBLK 64
#define NITER (S_LEN / KBLK)   // 32

// Q pre-scale: 1/sqrt(64) * log2(e), so scores feed exp2f directly
#define QSCALE 0.1803368801111244f

typedef __attribute__((ext_vector_type(8))) short short8;  // 8 x bf16
typedef __attribute__((ext_vector_type(4))) float f32x4;

// ---------------- fast-path LDS (64 KB exactly -> 2 blocks/CU, 16 waves) ----------------
#define KB_OFF   0        // 3 x 8KB K triple buffer
#define VT_OFF   24576    // 2 x 8KB Vt double buffer
#define PRED_OFF 40960    // 16KB pred bytes: [iter 32][row 64][8B]
#define P_OFF    57344    // 8KB P tile (Q staging in prologue; LP overlay at transition)
#define LP_OFF   57344    // 512B row-sum partials (inside P region, transient)
#define SMEM_BYTES 65536

// ---------------- fallback LDS layout ----------------
#define FK_OFF  0
#define FVT_OFF 16384
#define FP_OFF  24576
#define FMB_OFF 28672
#define FLP_OFF 36864
#define FSMEM_BYTES 37120

__device__ __forceinline__ int swz1(int row, int b) {
  return row * 128 + (b ^ ((row & 7) << 4));
}
__device__ __forceinline__ int swz2(int row, int b) {
  return row * 128 + (b ^ (((row >> 1) & 7) << 4));
}

__device__ __forceinline__ short f2b(float x) {  // fp32 -> bf16 RNE
  unsigned u = __float_as_uint(x);
  unsigned r = 0x7FFFu + ((u >> 16) & 1u);
  return (short)((u + r) >> 16);
}
__device__ __forceinline__ float b2f(short s) {
  return __uint_as_float(((unsigned)(unsigned short)s) << 16);
}

__device__ __forceinline__ void gload_lds16(const void* g, void* l) {
  __builtin_amdgcn_global_load_lds(
      (const __attribute__((address_space(1))) unsigned int*)g,
      (__attribute__((address_space(3))) unsigned int*)l, 16, 0, 0);
}

// counted-vmcnt barrier (T3/T4): loads/stores stay in flight across the barrier
#define WAITBAR(N) do { \
  asm volatile("s_waitcnt vmcnt(" #N ") lgkmcnt(0)" ::: "memory"); \
  __builtin_amdgcn_s_barrier(); } while (0)
#define LGKMBAR() do { \
  asm volatile("s_waitcnt lgkmcnt(0)" ::: "memory"); \
  __builtin_amdgcn_s_barrier(); } while (0)

// Detect mask element width (int32 words are in {0,1,0x3F800000}).
__global__ void detect_mask_kernel(const unsigned* m, int* flag) {
  unsigned v = m[blockIdx.x * 256 + threadIdx.x];
  if (v != 0u && v != 1u && v != 0x3F800000u) atomicOr(flag, 1);
}

// fp32 -> bf16, linear (for K)
__global__ void __launch_bounds__(256) convK_kernel(
    const float* __restrict__ in, short* __restrict__ out) {
  size_t i = ((size_t)blockIdx.x * 256 + threadIdx.x) * 8;
  float4 a = ((const float4*)(in + i))[0];
  float4 b = ((const float4*)(in + i))[1];
  short8 v;
  v[0] = f2b(a.x); v[1] = f2b(a.y); v[2] = f2b(a.z); v[3] = f2b(a.w);
  v[4] = f2b(b.x); v[5] = f2b(b.y); v[6] = f2b(b.z); v[7] = f2b(b.w);
  *(short8*)(out + i) = v;
}

// fp32 V[bh][s][d] -> bf16 Vt[bh][d][s]
__global__ void __launch_bounds__(256) convVT_kernel(
    const float* __restrict__ V, short* __restrict__ out) {
  __shared__ __align__(16) short t[64 * 72];
  int tid = threadIdx.x;
  int kb = blockIdx.x * 64, bh = blockIdx.y;
  const float* src = V + ((size_t)bh * S_LEN + kb) * D_HEAD;
#pragma unroll
  for (int j = 0; j < 4; ++j) {
    int key = j * 16 + (tid >> 4), d0 = (tid & 15) * 4;
    float4 f = *(const float4*)(src + (size_t)key * D_HEAD + d0);
    t[(d0 + 0) * 72 + key] = f2b(f.x);
    t[(d0 + 1) * 72 + key] = f2b(f.y);
    t[(d0 + 2) * 72 + key] = f2b(f.z);
    t[(d0 + 3) * 72 + key] = f2b(f.w);
  }
  __syncthreads();
  int row = tid >> 2, seg = tid & 3;
  short8 v0 = *(const short8*)(t + row * 72 + seg * 16);
  short8 v1 = *(const short8*)(t + row * 72 + seg * 16 + 8);
  short* dst = out + (size_t)bh * D_HEAD * S_LEN + (size_t)row * S_LEN + kb + seg * 16;
  *(short8*)dst = v0;
  *(short8*)(dst + 8) = v1;
}

// ======================= FAST PATH (QBLK=64, 8 waves, R11 schedule) =======================
template <bool BYTEMASK>
__device__ __forceinline__ void attn_fast(
    char* smem, const float* __restrict__ Qg, const void* __restrict__ maskg,
    const short* __restrict__ Kbf, const short* __restrict__ Vtb,
    float* __restrict__ ctxg, float* __restrict__ attng,
    int qb, int bh) {

  const int tid = threadIdx.x;
  const int w = tid >> 6, l = tid & 63;
  const int lg = l >> 4, li = l & 15;
  const int rh = w >> 1, ch = w & 1;          // wave -> (row-quarter, col-half)
  const int qbase = qb * QBLK;
  const int row = tid >> 3, seg = tid & 7;    // staging layout: 8 threads/row, 64 rows

  const float* Qp = Qg + ((size_t)bh * S_LEN + qbase) * D_HEAD;
  const short* Kbp = Kbf + (size_t)bh * S_LEN * D_HEAD;
  const short* Vtp = Vtb + (size_t)bh * D_HEAD * S_LEN;
  float* attnp = attng + ((size_t)bh * S_LEN + qbase) * S_LEN;
  float* ctxp  = ctxg  + ((size_t)bh * S_LEN + qbase) * D_HEAD;
  const size_t mbase = ((size_t)bh * S_LEN + qbase + row) * S_LEN + seg * 8;

  auto stageK = [&](int it) {               // -> kb[it % 3]; 1 instr/thread
    const int buf = it % 3;
    const short* src = Kbp + ((size_t)(it * KBLK + row)) * D_HEAD + ((seg ^ (row & 7)) * 8);
    int off = __builtin_amdgcn_readfirstlane(buf * 8192 + w * 1024);
    gload_lds16(src, smem + KB_OFF + off);
  };
  auto stageVt = [&](int it) {              // -> vt[it & 1]; 1 instr/thread
    const int buf = it & 1;
    const short* src = Vtp + (size_t)row * S_LEN + it * KBLK + ((seg ^ (row & 7)) * 8);
    int off = __builtin_amdgcn_readfirstlane(buf * 8192 + w * 1024);
    gload_lds16(src, smem + VT_OFF + off);
  };

  auto qkt = [&](f32x4* accs, const short8* qf, int it) {
    char* kb = smem + KB_OFF + (it % 3) * 8192;
#pragma unroll
    for (int ct = 0; ct < 2; ++ct) {
      int key = ch * 32 + ct * 16 + li;
      short8 b0 = *(const short8*)(kb + swz1(key, lg * 16));
      short8 b1 = *(const short8*)(kb + swz1(key, 64 + lg * 16));
      accs[ct] = __builtin_amdgcn_mfma_f32_16x16x32_bf16(qf[0], b0, accs[ct], 0, 0, 0);
      accs[ct] = __builtin_amdgcn_mfma_f32_16x16x32_bf16(qf[1], b1, accs[ct], 0, 0, 0);
    }
  };

  struct MaskRegs { int4 a, b; uint2 c; };
  auto loadMask = [&](int it, MaskRegs& m) {
    if constexpr (BYTEMASK) {
      m.c = *(const uint2*)((const unsigned char*)maskg + mbase + it * KBLK);
    } else {
      const int* p = (const int*)maskg + mbase + it * KBLK;
      m.a = *(const int4*)p;
      m.b = *(const int4*)(p + 4);
    }
  };
  auto predWrite = [&](int it, const MaskRegs& m) {
    unsigned pb = 0;
    if constexpr (BYTEMASK) {
      unsigned lo = m.c.x, hi = m.c.y;
#pragma unroll
      for (int j = 0; j < 4; ++j) {
        pb |= (((lo >> (8 * j)) & 255u) != 0u ? 1u : 0u) << j;
        pb |= (((hi >> (8 * j)) & 255u) != 0u ? 1u : 0u) << (j + 4);
      }
    } else {
      pb |= (m.a.x != 0) ? 1u : 0u;
      pb |= (m.a.y != 0) ? 2u : 0u;
      pb |= (m.a.z != 0) ? 4u : 0u;
      pb |= (m.a.w != 0) ? 8u : 0u;
      pb |= (m.b.x != 0) ? 16u : 0u;
      pb |= (m.b.y != 0) ? 32u : 0u;
      pb |= (m.b.z != 0) ? 64u : 0u;
      pb |= (m.b.w != 0) ? 128u : 0u;
    }
    *(unsigned char*)(smem + PRED_OFF + it * 512 + row * 8 + seg) = (unsigned char)pb;
  };

  // ---- prologue: issue mask + K loads early, stage Q (pre-scaled) ----
  MaskRegs t0, t1, mA, mB;
  loadMask(0, t0); loadMask(1, t1); loadMask(2, mA); loadMask(3, mB);
  stageK(0); stageK(1);
  {
    const float* src = Qp + row * D_HEAD + seg * 8;
    float4 a = ((const float4*)src)[0];
    float4 b = ((const float4*)src)[1];
    short8 v;
    v[0] = f2b(a.x * QSCALE); v[1] = f2b(a.y * QSCALE);
    v[2] = f2b(a.z * QSCALE); v[3] = f2b(a.w * QSCALE);
    v[4] = f2b(b.x * QSCALE); v[5] = f2b(b.y * QSCALE);
    v[6] = f2b(b.z * QSCALE); v[7] = f2b(b.w * QSCALE);
    *(short8*)(smem + P_OFF + swz1(row, seg * 16)) = v;
  }
  __syncthreads();   // Q visible; drains vmcnt(0) -> sK(0), sK(1) complete
  short8 qfrag[2];
  {
    int qr = rh * 16 + li;            // 0..63
    qfrag[0] = *(const short8*)(smem + P_OFF + swz1(qr, lg * 16));
    qfrag[1] = *(const short8*)(smem + P_OFF + swz1(qr, 64 + lg * 16));
  }
  predWrite(0, t0);
  predWrite(1, t1);

  // ===== pass 1: row sums of exp2(s); per-thread partials (reduce hoisted) =====
  float l_acc[4] = {0.f, 0.f, 0.f, 0.f};
  auto p1iter = [&](int i, MaskRegs& m) {
    f32x4 accs[2] = {{0.f,0.f,0.f,0.f},{0.f,0.f,0.f,0.f}};
    qkt(accs, qfrag, i);
    if (i <= 27) {
      if constexpr (BYTEMASK) WAITBAR(1); else WAITBAR(2);
    } else {
      WAITBAR(0);
    }
    if (i + 2 < NITER) stageK(i + 2);
    if (i + 2 < NITER) predWrite(i + 2, m);
    if (i + 4 < NITER) loadMask(i + 4, m);
#pragma unroll
    for (int reg = 0; reg < 4; ++reg) {
      int rw = rh * 16 + lg * 4 + reg;
      unsigned long long p64 =
          *(const unsigned long long*)(smem + PRED_OFF + i * 512 + rw * 8);
      unsigned pw = (unsigned)(p64 >> (ch << 5));
      float e0 = ((pw >> li) & 1u)        ? 0.f : exp2f(accs[0][reg]);
      float e1 = ((pw >> (16 + li)) & 1u) ? 0.f : exp2f(accs[1][reg]);
      l_acc[reg] += e0 + e1;              // reduce once after the loop
    }
  };
  for (int i = 0; i < NITER; i += 2) {
    p1iter(i, mA);
    p1iter(i + 1, mB);
  }

  // ---- transition: one-shot reduce, LP, prefetch pass-2 tiles ----
#pragma unroll
  for (int reg = 0; reg < 4; ++reg) {
    float s = l_acc[reg];
    s += __shfl_xor(s, 1);
    s += __shfl_xor(s, 2);
    s += __shfl_xor(s, 4);
    s += __shfl_xor(s, 8);
    l_acc[reg] = s;
  }
  if (li == 0) {
#pragma unroll
    for (int reg = 0; reg < 4; ++reg)
      *(float*)(smem + LP_OFF + ch * 256 + (rh * 16 + lg * 4 + reg) * 4) = l_acc[reg];
  }
  stageK(0); stageK(1); stageVt(0);
  WAITBAR(0);   // drain everything once; LP visible
  float linv[4];
#pragma unroll
  for (int reg = 0; reg < 4; ++reg) {
    int rw = rh * 16 + lg * 4 + reg;
    linv[reg] = 1.0f / (*(const float*)(smem + LP_OFF + rw * 4) +
                        *(const float*)(smem + LP_OFF + 256 + rw * 4));
  }
  float* arow = attnp + (size_t)row * S_LEN + seg * 8;

  // ===== pass 2: recompute S, P->LDS, contiguous attn store-back, PV =====
  f32x4 acco[2] = {{0.f,0.f,0.f,0.f},{0.f,0.f,0.f,0.f}};
  for (int i = 0; i < NITER; ++i) {
    f32x4 accs[2] = {{0.f,0.f,0.f,0.f},{0.f,0.f,0.f,0.f}};
    qkt(accs, qfrag, i);
    // BARRIER_A (lgkm only): all waves past qkt(i)/PV(i-1)/store-back reads -> WAR safe
    LGKMBAR();
    if (i + 2 < NITER) stageK(i + 2);
    if (i + 1 < NITER) stageVt(i + 1);
#pragma unroll
    for (int reg = 0; reg < 4; ++reg) {
      int rw = rh * 16 + lg * 4 + reg;
      unsigned long long p64 =
          *(const unsigned long long*)(smem + PRED_OFF + i * 512 + rw * 8);
      unsigned pw = (unsigned)(p64 >> (ch << 5));
      float e0 = ((pw >> li) & 1u)        ? 0.f : exp2f(accs[0][reg]) * linv[reg];
      float e1 = ((pw >> (16 + li)) & 1u) ? 0.f : exp2f(accs[1][reg]) * linv[reg];
      *(short*)(smem + P_OFF + swz2(rw, (ch * 32 + li) * 2)) = f2b(e0);
      *(short*)(smem + P_OFF + swz2(rw, (ch * 32 + 16 + li) * 2)) = f2b(e1);
    }
    // BARRIER_B: P visible; drain through sVt(i)/sK(i+1); keep stores + newer in flight
    if (i == 0) WAITBAR(2);
    else if (i <= 29) WAITBAR(4);
    else if (i == 30) WAITBAR(3);
    else WAITBAR(2);
    // attn store-back from LDS: 256B contiguous per 8-lane row group
    {
      short8 pv = *(const short8*)(smem + P_OFF + swz2(row, seg * 16));
      float4 f0, f1;
      f0.x = b2f(pv[0]); f0.y = b2f(pv[1]); f0.z = b2f(pv[2]); f0.w = b2f(pv[3]);
      f1.x = b2f(pv[4]); f1.y = b2f(pv[5]); f1.z = b2f(pv[6]); f1.w = b2f(pv[7]);
      ((float4*)(arow + i * KBLK))[0] = f0;
      *(float4*)(arow + i * KBLK + 4) = f1;
    }
    // PV: O(16x32 per wave) += P(16x64) * V(64xD tile)
    {
      char* vb = smem + VT_OFF + (i & 1) * 8192;
#pragma unroll
      for (int ks = 0; ks < 2; ++ks) {
        int prow = rh * 16 + li;
        short8 af = *(const short8*)(smem + P_OFF + swz2(prow, ks * 64 + lg * 16));
#pragma unroll
        for (int ct2 = 0; ct2 < 2; ++ct2) {
          int d = ch * 32 + ct2 * 16 + li;
          short8 bf = *(const short8*)(vb + swz1(d, ks * 64 + lg * 16));
          acco[ct2] = __builtin_amdgcn_mfma_f32_16x16x32_bf16(af, bf, acco[ct2], 0, 0, 0);
        }
      }
    }
  }

  // epilogue: P was normalized -> ctx = acco
#pragma unroll
  for (int ct2 = 0; ct2 < 2; ++ct2)
#pragma unroll
    for (int reg = 0; reg < 4; ++reg) {
      int rw = rh * 16 + lg * 4 + reg;
      int d = ch * 32 + ct2 * 16 + li;
      ctxp[(size_t)rw * D_HEAD + d] = acco[ct2][reg];
    }
}

__global__ void __launch_bounds__(512, 4)
attn_fast_kernel(const float* Q, const void* M, const short* Kbf, const short* Vtb,
                 float* ctx, float* attn, const int* flag) {
  __shared__ __align__(16) char smem[SMEM_BYTES];
  int bid = blockIdx.x;
  int s = ((bid & 7) << 8) | (bid >> 3);   // XCD-bijective swizzle (2048 = 8*256)
  int bh = s >> 5, qb = s & 31;            // 32 q-blocks of 64 rows per head
  if (*flag)
    attn_fast<true>(smem, Q, M, Kbf, Vtb, ctx, attn, qb, bh);
  else
    attn_fast<false>(smem, Q, M, Kbf, Vtb, ctx, attn, qb, bh);
}

// ======================= FALLBACK (round-2 body; no workspace needed) =======================
template <bool BYTEMASK>
__device__ __forceinline__ void attn_body(
    char* smem, const float* Qg, const float* Kg, const float* Vg,
    const void* maskg, float* ctxg, float* attng) {

  const int tid = threadIdx.x;
  const int w = tid >> 6, l = tid & 63;
  const int lg = l >> 4, li = l & 15;
  const int rh = w >> 1, ch = w & 1;
  const int qb = blockIdx.x, bh = blockIdx.y;
  const int qbase = qb * 32;

  const float* Qp = Qg + ((size_t)bh * S_LEN + qbase) * D_HEAD;
  const float* Kp = Kg + (size_t)bh * S_LEN * D_HEAD;
  const float* Vp = Vg + (size_t)bh * S_LEN * D_HEAD;
  float* attnp = attng + ((size_t)bh * S_LEN + qbase) * S_LEN;
  float* ctxp  = ctxg  + ((size_t)bh * S_LEN + qbase) * D_HEAD;
  const size_t mrow0 = ((size_t)bh * S_LEN + qbase) * S_LEN;

  auto stageK = [&](int it, int buf) {
    char* kb = smem + FK_OFF + buf * 8192;
    int key = tid >> 2, seg = tid & 3;
    const float* src = Kp + ((size_t)(it * KBLK + key)) * D_HEAD + seg * 16;
    float4 f0 = ((const float4*)src)[0];
    float4 f1 = ((const float4*)src)[1];
    float4 f2 = ((const float4*)src)[2];
    float4 f3 = ((const float4*)src)[3];
    short8 v0, v1;
    v0[0] = f2b(f0.x); v0[1] = f2b(f0.y); v0[2] = f2b(f0.z); v0[3] = f2b(f0.w);
    v0[4] = f2b(f1.x); v0[5] = f2b(f1.y); v0[6] = f2b(f1.z); v0[7] = f2b(f1.w);
    v1[0] = f2b(f2.x); v1[1] = f2b(f2.y); v1[2] = f2b(f2.z); v1[3] = f2b(f2.w);
    v1[4] = f2b(f3.x); v1[5] = f2b(f3.y); v1[6] = f2b(f3.z); v1[7] = f2b(f3.w);
    *(short8*)(kb + swz1(key, seg * 32)) = v0;
    *(short8*)(kb + swz1(key, seg * 32 + 16)) = v1;
  };

  auto stageVt = [&](int it) {
    char* vb = smem + FVT_OFF;
    int key = l, db = w;
    const float* src = Vp + ((size_t)(it * KBLK + key)) * D_HEAD + db * 16;
#pragma unroll
    for (int j = 0; j < 4; ++j) {
      float4 f = ((const float4*)src)[j];
      int dd = db * 16 + j * 4;
      *(short*)(vb + swz1(dd + 0, key * 2)) = f2b(f.x);
      *(short*)(vb + swz1(dd + 1, key * 2)) = f2b(f.y);
      *(short*)(vb + swz1(dd + 2, key * 2)) = f2b(f.z);
      *(short*)(vb + swz1(dd + 3, key * 2)) = f2b(f.w);
    }
  };

  auto loadMask = [&](int it, unsigned* m) {
#pragma unroll
    for (int reg = 0; reg < 4; ++reg) {
      int rw = rh * 16 + lg * 4 + reg;
#pragma unroll
      for (int ct = 0; ct < 2; ++ct) {
        size_t idx = mrow0 + (size_t)rw * S_LEN + it * KBLK + ch * 32 + ct * 16 + li;
        if constexpr (BYTEMASK)
          m[ct * 4 + reg] = (unsigned)((const unsigned char*)maskg)[idx];
        else
          m[ct * 4 + reg] = ((const unsigned*)maskg)[idx];
      }
    }
  };

  auto qkt = [&](f32x4* accs, const short8* qf, int buf) {
    char* kb = smem + FK_OFF + buf * 8192;
#pragma unroll
    for (int ct = 0; ct < 2; ++ct) {
      int key = ch * 32 + ct * 16 + li;
      short8 b0 = *(const short8*)(kb + swz1(key, lg * 16));
      short8 b1 = *(const short8*)(kb + swz1(key, 64 + lg * 16));
      accs[ct] = __builtin_amdgcn_mfma_f32_16x16x32_bf16(qf[0], b0, accs[ct], 0, 0, 0);
      accs[ct] = __builtin_amdgcn_mfma_f32_16x16x32_bf16(qf[1], b1, accs[ct], 0, 0, 0);
    }
  };

  stageK(0, 0);
  unsigned mc[8];
  loadMask(0, mc);
  {
    int rw = tid >> 3, seg = tid & 7;
    const float* src = Qp + rw * D_HEAD + seg * 8;
    float4 a = ((const float4*)src)[0];
    float4 b = ((const float4*)src)[1];
    short8 v;
    v[0] = f2b(a.x); v[1] = f2b(a.y); v[2] = f2b(a.z); v[3] = f2b(a.w);
    v[4] = f2b(b.x); v[5] = f2b(b.y); v[6] = f2b(b.z); v[7] = f2b(b.w);
    *(short8*)(smem + FP_OFF + swz1(rw, seg * 16)) = v;
  }
  __syncthreads();
  short8 qfrag[2];
  {
    int rw = rh * 16 + li;
    qfrag[0] = *(const short8*)(smem + FP_OFF + swz1(rw, lg * 16));
    qfrag[1] = *(const short8*)(smem + FP_OFF + swz1(rw, 64 + lg * 16));
  }
  __syncthreads();

  float l_acc[4] = {0.f, 0.f, 0.f, 0.f};
  for (int it = 0; it < NITER; ++it) {
    const int cb = it & 1, nb = cb ^ 1;
    if (it + 1 < NITER) stageK(it + 1, nb);
    unsigned mn[8];
    if (it + 1 < NITER) loadMask(it + 1, mn);
    f32x4 accs[2] = {{0.f,0.f,0.f,0.f},{0.f,0.f,0.f,0.f}};
    qkt(accs, qfrag, cb);
    unsigned mbyte = 0;
#pragma unroll
    for (int reg = 0; reg < 4; ++reg) {
      float contrib = 0.f;
#pragma unroll
      for (int ct = 0; ct < 2; ++ct) {
        bool pred = mc[ct * 4 + reg] != 0u;
        mbyte |= (unsigned)pred << (ct * 4 + reg);
        float pp = pred ? 0.f : __expf(accs[ct][reg] * 0.125f);
        contrib += pp;
      }
      contrib += __shfl_xor(contrib, 1);
      contrib += __shfl_xor(contrib, 2);
      contrib += __shfl_xor(contrib, 4);
      contrib += __shfl_xor(contrib, 8);
      l_acc[reg] += contrib;
    }
    *(unsigned char*)(smem + FMB_OFF + it * 256 + tid) = (unsigned char)mbyte;
    __syncthreads();
    if (it + 1 < NITER) {
#pragma unroll
      for (int i = 0; i < 8; ++i) mc[i] = mn[i];
    }
  }

  if (li == 0) {
#pragma unroll
    for (int reg = 0; reg < 4; ++reg)
      *(float*)(smem + FLP_OFF + ch * 128 + (rh * 16 + lg * 4 + reg) * 4) = l_acc[reg];
  }
  stageK(0, 0);
  stageVt(0);
  __syncthreads();
  float linv[4];
#pragma unroll
  for (int reg = 0; reg < 4; ++reg) {
    int rw = rh * 16 + lg * 4 + reg;
    linv[reg] = 1.0f / (*(const float*)(smem + FLP_OFF + rw * 4) +
                        *(const float*)(smem + FLP_OFF + 128 + rw * 4));
  }

  f32x4 acco[2] = {{0.f,0.f,0.f,0.f},{0.f,0.f,0.f,0.f}};
  for (int it = 0; it < NITER; ++it) {
    const int cb = it & 1, nb = cb ^ 1;
    if (it > 0) stageVt(it);
    if (it + 1 < NITER) stageK(it + 1, nb);
    f32x4 accs[2] = {{0.f,0.f,0.f,0.f},{0.f,0.f,0.f,0.f}};
    qkt(accs, qfrag, cb);
    unsigned mbyte = *(const unsigned char*)(smem + FMB_OFF + it * 256 + tid);
#pragma unroll
    for (int reg = 0; reg < 4; ++reg) {
      int rw = rh * 16 + lg * 4 + reg;
#pragma unroll
      for (int ct = 0; ct < 2; ++ct) {
        int col = ch * 32 + ct * 16 + li;
        bool pred = (mbyte >> (ct * 4 + reg)) & 1u;
        float pp = pred ? 0.f : __expf(accs[ct][reg] * 0.125f) * linv[reg];
        attnp[(size_t)rw * S_LEN + it * KBLK + col] = pp;
        *(short*)(smem + FP_OFF + swz2(rw, col * 2)) = f2b(pp);
      }
    }
    __syncthreads();
#pragma unroll
    for (int ks = 0; ks < 2; ++ks) {
      int prow = rh * 16 + li;
      short8 af = *(const short8*)(smem + FP_OFF + swz2(prow, ks * 64 + lg * 16));
#pragma unroll
      for (int ct2 = 0; ct2 < 2; ++ct2) {
        int d = ch * 32 + ct2 * 16 + li;
        short8 bf = *(const short8*)(smem + FVT_OFF + swz1(d, ks * 64 + lg * 16));
        acco[ct2] = __builtin_amdgcn_mfma_f32_16x16x32_bf16(af, bf, acco[ct2], 0, 0, 0);
      }
    }
    __syncthreads();
  }

#pragma unroll
  for (int ct2 = 0; ct2 < 2; ++ct2) {
#pragma unroll
    for (int reg = 0; reg < 4; ++reg) {
      int rw = rh * 16 + lg * 4 + reg;
      int d = ch * 32 + ct2 * 16 + li;
      ctxp[(size_t)rw * D_HEAD + d] = acco[ct2][reg];
    }
  }
}

__global__ void __launch_bounds__(256, 4)
attn_kernel(const float* Q, const float* K, const float* V, const void* M,
            float* ctx, float* attn, const int* flag) {
  extern __shared__ char smem[];
  if (*flag)
    attn_body<true>(smem, Q, K, V, M, ctx, attn);
  else
    attn_body<false>(smem, Q, K, V, M, ctx, attn);
}

extern "C" void kernel_launch(void* const* d_in, const int* in_sizes, int n_in,
                              void* d_out, int out_size, void* d_ws, size_t ws_size,
                              hipStream_t stream) {
  const float* Q = (const float*)d_in[0];
  const float* K = (const float*)d_in[1];
  const float* V = (const float*)d_in[2];
  const void*  M = d_in[3];
  float* ctx  = (float*)d_out;
  float* attn = ctx + (size_t)NBH * S_LEN * D_HEAD;
  int* flag = (int*)d_ws;
  short* Kbf = (short*)((char*)d_ws + 256);
  short* Vtb = Kbf + (size_t)NBH * S_LEN * D_HEAD;
  const size_t PRE_BYTES = 256 + (size_t)2 * NBH * S_LEN * D_HEAD * sizeof(short);

  hipMemsetAsync(flag, 0, sizeof(int), stream);
  detect_mask_kernel<<<dim3(16), dim3(256), 0, stream>>>((const unsigned*)M, flag);

  if (ws_size >= PRE_BYTES) {
    convK_kernel<<<dim3(4096), dim3(256), 0, stream>>>(K, Kbf);
    convVT_kernel<<<dim3(32, 64), dim3(256), 0, stream>>>(V, Vtb);
    attn_fast_kernel<<<dim3(2048), dim3(512), 0, stream>>>(
        Q, M, Kbf, Vtb, ctx, attn, flag);
  } else {
    dim3 grid(S_LEN / 32, NBH);
    attn_kernel<<<grid, dim3(256), FSMEM_BYTES, stream>>>(
        Q, K, V, M, ctx, attn, flag);
  }
}